// Round 3
// baseline (3052.734 us; speedup 1.0000x reference)
//
#include <hip/hip_runtime.h>
#include <cstdint>
#include <cstddef>

#define HW    1444      // 38*38
#define NA    12996     // HW*9
#define NPRE  3000
#define NW    47        // ceil(3000/64)
#define NPOST 300

// d_out section offsets (in floats)
#define OFF_LOCS   0         // 4*12996*4 = 207936
#define OFF_SCORES 207936    // 4*12996*2 = 103968
#define OFF_ROIS   311904    // 1200*4    = 4800
#define OFF_IDX    316704    // 4*300     = 1200
#define OFF_ANCH   317904    // 12996*4   = 51984

#define INVALID_KEY 0xFFF0000000000000ULL

__device__ inline double as_dim(int raw) {
  if (raw > 0 && raw < 1000000) return (double)raw;
  return (double)__int_as_float(raw);
}

// ---------------- W transpose: Wt[c*64 + o], o<36 loc, 36..53 score ----------
__global__ __launch_bounds__(256) void wt_k(const float* __restrict__ lw,
                                            const float* __restrict__ sw,
                                            float* __restrict__ Wt) {
  int t = blockIdx.x * 256 + threadIdx.x;
  if (t >= 64 * 512) return;
  int o = t & 63, c = t >> 6;
  float v = 0.f;
  if (o < 36)      v = lw[o * 512 + c];
  else if (o < 54) v = sw[(o - 36) * 512 + c];
  Wt[t] = v;
}

// ------- 3x3 conv + bias + relu, fp64 accumulation, 2 output rows/thread ----
__global__ __launch_bounds__(256) void conv_k(const float* __restrict__ X,
                                              const float* __restrict__ W,
                                              const float* __restrict__ B,
                                              float* __restrict__ F) {
  int t = blockIdx.x * 256 + threadIdx.x;   // over 19*38 = 722 half-rows
  if (t >= 19 * 38) return;
  int o = blockIdx.y, n = blockIdx.z;
  int yh = t / 38, xx = t - yh * 38;
  int y0 = yh * 2;
  const float* xn = X + ((size_t)n * 512) * HW;
  const float* wo = W + ((size_t)o * 512) * 9;

  int roff[4]; float rmask[4];
#pragma unroll
  for (int k = 0; k < 4; ++k) {
    int r = y0 - 1 + k;
    rmask[k] = (r >= 0 && r < 38) ? 1.f : 0.f;
    int rc = r < 0 ? 0 : (r > 37 ? 37 : r);
    roff[k] = rc * 38;
  }
  int coff[3]; float cmask[3];
#pragma unroll
  for (int k = 0; k < 3; ++k) {
    int cc = xx - 1 + k;
    cmask[k] = (cc >= 0 && cc < 38) ? 1.f : 0.f;
    coff[k] = cc < 0 ? 0 : (cc > 37 ? 37 : cc);
  }
  float m[4][3];
#pragma unroll
  for (int a = 0; a < 4; ++a)
#pragma unroll
    for (int b = 0; b < 3; ++b) m[a][b] = rmask[a] * cmask[b];

  double acc0 = 0., acc1 = 0.;
  for (int c = 0; c < 512; ++c) {
    const float* xp = xn + c * HW;
    const float* wp = wo + c * 9;   // wave-uniform -> scalar loads
    double v[4][3];
#pragma unroll
    for (int a = 0; a < 4; ++a)
#pragma unroll
      for (int b = 0; b < 3; ++b)
        v[a][b] = (double)(xp[roff[a] + coff[b]] * m[a][b]);  // mask mul exact
#pragma unroll
    for (int kh = 0; kh < 3; ++kh)
#pragma unroll
      for (int kw = 0; kw < 3; ++kw) {
        double wv = (double)wp[kh * 3 + kw];
        acc0 = fma(wv, v[kh][kw],     acc0);
        acc1 = fma(wv, v[kh + 1][kw], acc1);
      }
  }
  double bb = (double)B[o];
  float* fp = F + ((size_t)(n * 512 + o)) * HW;
  fp[y0 * 38 + xx]       = (float)fmax(acc0 + bb, 0.0);
  fp[(y0 + 1) * 38 + xx] = (float)fmax(acc1 + bb, 0.0);
}

// ------- 1x1 heads (fp64) + bias + layout transform + fp64 softmax fg -------
__global__ __launch_bounds__(256) void heads_k(const float* __restrict__ F,
                                               const float* __restrict__ Wt,
                                               const float* __restrict__ lb,
                                               const float* __restrict__ sb,
                                               float* __restrict__ out,
                                               double* __restrict__ fg) {
  __shared__ float sf[512 * 4];
  __shared__ double ssc[4][18];
  int n = blockIdx.y;
  int p0 = blockIdx.x * 4;
  int tid = threadIdx.x;
  const float* fn = F + ((size_t)n * 512) * HW;
  for (int e = tid; e < 2048; e += 256) {
    int c = e >> 2, pl = e & 3;
    sf[e] = fn[c * HW + p0 + pl];
  }
  __syncthreads();
  int pl = tid & 3, o = tid >> 2;
  double acc = 0.;
  if (o < 54) {
    for (int c = 0; c < 512; ++c)
      acc = fma((double)Wt[(c << 6) | o], (double)sf[(c << 2) | pl], acc);
  }
  int p = p0 + pl;
  if (o < 36) {
    acc += (double)lb[o];
    out[OFF_LOCS + ((size_t)n * NA + (size_t)p * 9 + (o >> 2)) * 4 + (o & 3)] = (float)acc;
  } else if (o < 54) {
    int oo = o - 36;
    acc += (double)sb[oo];
    out[OFF_SCORES + ((size_t)n * NA + (size_t)p * 9 + (oo >> 1)) * 2 + (oo & 1)] = (float)acc;
    ssc[pl][oo] = acc;
  }
  __syncthreads();
  if (tid < 36) {
    int pl2 = tid / 9, a = tid - pl2 * 9;
    double s0 = ssc[pl2][a * 2], s1 = ssc[pl2][a * 2 + 1];
    double mx = fmax(s0, s1);
    double e0 = exp(s0 - mx), e1 = exp(s1 - mx);
    fg[(size_t)n * NA + (size_t)(p0 + pl2) * 9 + a] = e1 / (e0 + e1);
  }
}

// ---------------- anchors -> d_out anchor section ---------------------------
__global__ __launch_bounds__(256) void anchor_k(float* __restrict__ out) {
  int i = blockIdx.x * 256 + threadIdx.x;
  if (i >= NA) return;
  int p = i / 9, a = i - p * 9;
  int ri = a / 3, si = a - ri * 3;
  double sr  = (ri == 0) ? 0.7071067811865476 : (ri == 1 ? 1.0 : 1.4142135623730951);
  double sri = (ri == 0) ? 1.4142135623730951 : (ri == 1 ? 1.0 : 0.7071067811865476);
  double hs = (double)(128 << si) * sr;   // 16*scale*sqrt(r)
  double wd = (double)(128 << si) * sri;  // 16*scale*sqrt(1/r)
  int py = p / 38, px = p - py * 38;
  float sx = (float)(px * 16), sy = (float)(py * 16);
  float x1 = (float)(8.0 - 0.5 * wd), y1 = (float)(8.0 - 0.5 * hs);
  float x2 = (float)(8.0 + 0.5 * wd), y2 = (float)(8.0 + 0.5 * hs);
  float* ap = out + OFF_ANCH + (size_t)i * 4;
  ap[0] = sx + x1; ap[1] = sy + y1; ap[2] = sx + x2; ap[3] = sy + y2;
}

// ---------------- decode boxes (fp64) + valid + sort keys -------------------
__global__ __launch_bounds__(256) void decode_k(const float* __restrict__ out,
                                                const double* __restrict__ fg,
                                                const int* __restrict__ ihp,
                                                const int* __restrict__ iwp,
                                                double* __restrict__ boxes,
                                                unsigned long long* __restrict__ keys) {
  int t = blockIdx.x * 256 + threadIdx.x;   // 4*16384 exactly
  int n = t >> 14, i = t & 16383;
  if (i >= NA) { keys[t] = ~0ULL; return; }
  const float* ap = out + OFF_ANCH + (size_t)i * 4;
  double ax1 = ap[0], ay1 = ap[1], ax2 = ap[2], ay2 = ap[3];
  double aw = ax2 - ax1, ah = ay2 - ay1;
  double acx = ax1 + 0.5 * aw, acy = ay1 + 0.5 * ah;
  const float* lp = out + OFF_LOCS + ((size_t)n * NA + i) * 4;
  double cx = (double)lp[0] * aw + acx, cy = (double)lp[1] * ah + acy;
  double bw = aw * exp((double)lp[2]), bh = ah * exp((double)lp[3]);
  double iwf = as_dim(iwp[0]), ihf = as_dim(ihp[0]);
  double x1 = fmin(fmax(cx - 0.5 * bw, 0.0), iwf);
  double y1 = fmin(fmax(cy - 0.5 * bh, 0.0), ihf);
  double x2 = fmin(fmax(cx + 0.5 * bw, 0.0), iwf);
  double y2 = fmin(fmax(cy + 0.5 * bh, 0.0), ihf);
  bool valid = ((x2 - x1) >= 16.0) && ((y2 - y1) >= 16.0);
  double* bp = boxes + ((size_t)n * NA + i) * 4;
  bp[0] = x1; bp[1] = y1; bp[2] = x2; bp[3] = y2;
  double sc = fg[(size_t)n * NA + i];
  unsigned long long u = (unsigned long long)__double_as_longlong(sc);
  u = (u >> 63) ? ~u : (u | 0x8000000000000000ULL);  // ascending-sortable
  unsigned long long inv = ~u;                       // descending
  if (!valid) inv = INVALID_KEY;
  keys[t] = (inv & ~0x3FFFULL) | (unsigned long long)i;  // 50-bit score + idx
}

// ---------------- bitonic sort 16384 keys per batch (1 block/batch) ---------
__global__ __launch_bounds__(1024) void sort_k(unsigned long long* __restrict__ keys) {
  unsigned long long* k = keys + ((size_t)blockIdx.x << 14);
  int tid = threadIdx.x;
  for (int size = 2; size <= 16384; size <<= 1) {
    for (int stride = size >> 1; stride > 0; stride >>= 1) {
      __syncthreads();
      for (int t = tid; t < 8192; t += 1024) {
        int lo = t & (stride - 1);
        int i1 = ((t - lo) << 1) | lo;
        int i2 = i1 + stride;
        bool up = (i1 & size) == 0;
        unsigned long long a = k[i1], b = k[i2];
        if ((a > b) == up) { k[i1] = b; k[i2] = a; }
      }
    }
  }
}

// ---------------- gather sorted top-3000 boxes + valid bit-words ------------
__global__ void gather_k(const unsigned long long* __restrict__ keys,
                         const double* __restrict__ boxes,
                         double* __restrict__ bsort,
                         unsigned long long* __restrict__ vw) {
  int n = blockIdx.y, w = blockIdx.x, l = threadIdx.x;  // 47 x 4 blocks, 64 thr
  int r = w * 64 + l;
  bool valid = false;
  if (r < NPRE) {
    unsigned long long kk = keys[((size_t)n << 14) + r];
    valid = kk < INVALID_KEY;
    unsigned idx = (unsigned)(kk & 0x3FFFULL);
    const double* bp = boxes + ((size_t)n * NA + idx) * 4;
    double* dp = bsort + ((size_t)n * NPRE + r) * 4;
    dp[0] = bp[0]; dp[1] = bp[1]; dp[2] = bp[2]; dp[3] = bp[3];
  }
  unsigned long long mask = __ballot(valid);
  if (l == 0) vw[n * NW + w] = mask;
}

// ------- suppression matrix (fp64 IoU): bit j set iff j>i && iou>0.7 --------
__global__ __launch_bounds__(256) void iou_k(const double* __restrict__ bsort,
                                             unsigned long long* __restrict__ sup) {
  int t = blockIdx.x * 256 + threadIdx.x;
  if (t >= 4 * NPRE * NW) return;
  int w = t % NW; int rest = t / NW; int i = rest % NPRE; int n = rest / NPRE;
  const double* bb = bsort + (size_t)n * NPRE * 4;
  double bix1 = bb[(size_t)i*4], biy1 = bb[(size_t)i*4+1];
  double bix2 = bb[(size_t)i*4+2], biy2 = bb[(size_t)i*4+3];
  double ai = (bix2 - bix1) * (biy2 - biy1);
  unsigned long long word = 0ULL;
  int j0 = w << 6;
  if (j0 + 63 > i) {
    int lmax = NPRE - j0; if (lmax > 64) lmax = 64;
    for (int l = 0; l < lmax; ++l) {
      int j = j0 + l;
      if (j <= i) continue;
      const double* bj = bb + (size_t)j * 4;
      double aj = (bj[2] - bj[0]) * (bj[3] - bj[1]);
      double xx1 = fmax(bix1, bj[0]), yy1 = fmax(biy1, bj[1]);
      double xx2 = fmin(bix2, bj[2]), yy2 = fmin(biy2, bj[3]);
      double inter = fmax(xx2 - xx1, 0.0) * fmax(yy2 - yy1, 0.0);
      double uni = ai + aj - inter;
      double iou = (uni > 0.0) ? inter / uni : 0.0;
      word |= (unsigned long long)(iou > 0.7) << l;
    }
  }
  sup[((size_t)n * NPRE + i) * NW + w] = word;
}

// ---------------- sequential NMS scan (1 wave/batch) + emit rois ------------
__global__ void nms_k(const unsigned long long* __restrict__ sup,
                      const unsigned long long* __restrict__ vwp,
                      const double* __restrict__ bsort,
                      float* __restrict__ out) {
  int n = blockIdx.x; int l = threadIdx.x;   // 64 threads = 1 wave
  unsigned long long vw = (l < NW) ? vwp[n * NW + l] : 0ULL;
  unsigned long long remv = 0ULL;
  const unsigned long long* srow = sup + (size_t)n * NPRE * NW;
#pragma unroll 4
  for (int i = 0; i < NPRE; ++i) {
    unsigned long long row = (l < NW) ? srow[(size_t)i * NW + l] : 0ULL;
    unsigned long long kwv = vw & ~remv;
    unsigned long long kb = __shfl(kwv, i >> 6);
    if ((kb >> (i & 63)) & 1ULL) remv |= row;
  }
  unsigned long long keep = vw & ~remv;
  int cnt = __popcll(keep);
  int pre = cnt;
#pragma unroll
  for (int d = 1; d < 64; d <<= 1) {
    int tt = __shfl_up(pre, d);
    if (l >= d) pre += tt;
  }
  int nk = __shfl(pre, 63);
  int excl = pre - cnt;
  __shared__ float sbox[NPOST * 4];
  unsigned long long m = keep; int rank = excl;
  while (m) {
    int b = __builtin_ctzll(m);
    m &= m - 1;
    if (rank < NPOST) {
      int j = (l << 6) + b;
      const double* bj = bsort + ((size_t)n * NPRE + j) * 4;
      sbox[rank*4]   = (float)bj[0]; sbox[rank*4+1] = (float)bj[1];
      sbox[rank*4+2] = (float)bj[2]; sbox[rank*4+3] = (float)bj[3];
    }
    ++rank;
  }
  __syncthreads();
  if (nk == 0 && l == 0) {
    const double* b0 = bsort + (size_t)n * NPRE * 4;
    sbox[0] = (float)b0[0]; sbox[1] = (float)b0[1];
    sbox[2] = (float)b0[2]; sbox[3] = (float)b0[3];
  }
  __syncthreads();
  int nke = nk > 0 ? nk : 1;
  for (int r = l; r < NPOST; r += 64) {
    int src = r < nke ? r : r % nke;
    float4 b4 = *(float4*)(sbox + src * 4);
    *(float4*)(out + OFF_ROIS + ((size_t)n * NPOST + r) * 4) = b4;
    out[OFF_IDX + n * NPOST + r] = (float)n;
  }
}

extern "C" void kernel_launch(void* const* d_in, const int* in_sizes, int n_in,
                              void* d_out, int out_size, void* d_ws, size_t ws_size,
                              hipStream_t stream) {
  const float* X  = (const float*)d_in[0];
  const float* CW = (const float*)d_in[1];
  const float* CB = (const float*)d_in[2];
  const float* SW = (const float*)d_in[3];
  const float* SB = (const float*)d_in[4];
  const float* LW = (const float*)d_in[5];
  const float* LB = (const float*)d_in[6];
  const int*   IH = (const int*)d_in[7];
  const int*   IW = (const int*)d_in[8];
  float* out = (float*)d_out;
  char* ws = (char*)d_ws;

  // ws carve. sup OVERLAYS feat (feat dead after heads_k). Peak: 14,949,504 B.
  float* feat = (float*)(ws + 0);                                  // 11,829,248
  unsigned long long* sup  = (unsigned long long*)(ws + 0);        //  4,512,000 (overlay)
  float* Wt    = (float*)(ws + 11829248);                          //    131,072
  double* fg   = (double*)(ws + 11960320);                         //    415,872
  double* boxes= (double*)(ws + 12376192);                         //  1,663,488
  unsigned long long* keys = (unsigned long long*)(ws + 14039680); //    524,288
  double* bsort= (double*)(ws + 14563968);                         //    384,000
  unsigned long long* vw   = (unsigned long long*)(ws + 14947968); //      1,536

  hipLaunchKernelGGL(wt_k,     dim3(128),        dim3(256),  0, stream, LW, SW, Wt);
  hipLaunchKernelGGL(conv_k,   dim3(3, 512, 4),  dim3(256),  0, stream, X, CW, CB, feat);
  hipLaunchKernelGGL(heads_k,  dim3(361, 4),     dim3(256),  0, stream, feat, Wt, LB, SB, out, fg);
  hipLaunchKernelGGL(anchor_k, dim3(51),         dim3(256),  0, stream, out);
  hipLaunchKernelGGL(decode_k, dim3(256),        dim3(256),  0, stream, out, fg, IH, IW, boxes, keys);
  hipLaunchKernelGGL(sort_k,   dim3(4),          dim3(1024), 0, stream, keys);
  hipLaunchKernelGGL(gather_k, dim3(47, 4),      dim3(64),   0, stream, keys, boxes, bsort, vw);
  hipLaunchKernelGGL(iou_k,    dim3((4*NPRE*NW + 255) / 256), dim3(256), 0, stream, bsort, sup);
  hipLaunchKernelGGL(nms_k,    dim3(4),          dim3(64),   0, stream, sup, vw, bsort, out);
}

// Round 4
// 1853.391 us; speedup vs baseline: 1.6471x; 1.6471x over previous
//
#include <hip/hip_runtime.h>
#include <cstdint>
#include <cstddef>

#define HW    1444      // 38*38
#define NA    12996     // HW*9
#define NPRE  3000
#define NW    47        // ceil(3000/64)
#define NPOST 300

// d_out section offsets (in floats)
#define OFF_LOCS   0         // 4*12996*4 = 207936
#define OFF_SCORES 207936    // 4*12996*2 = 103968
#define OFF_ROIS   311904    // 1200*4    = 4800
#define OFF_IDX    316704    // 4*300     = 1200
#define OFF_ANCH   317904    // 12996*4   = 51984

#define INVALID_KEY 0xFFF0000000000000ULL

__device__ inline double as_dim(int raw) {
  if (raw > 0 && raw < 1000000) return (double)raw;
  return (double)__int_as_float(raw);
}

// ---------------- W transpose: Wt[c*64 + o], o<36 loc, 36..53 score ----------
__global__ __launch_bounds__(256) void wt_k(const float* __restrict__ lw,
                                            const float* __restrict__ sw,
                                            float* __restrict__ Wt) {
  int t = blockIdx.x * 256 + threadIdx.x;
  if (t >= 64 * 512) return;
  int o = t & 63, c = t >> 6;
  float v = 0.f;
  if (o < 36)      v = lw[o * 512 + c];
  else if (o < 54) v = sw[(o - 36) * 512 + c];
  Wt[t] = v;
}

// ------- 3x3 conv, f64 acc, LDS-tiled: lanes=64 o, 20 px/thread -------------
// block: 64 o  x  2 rows x 38 cols. wave w: row r_off=w>>1, col seg=(w&1)*20.
// Tap order (ky,kx) per ascending c == R3 kernel -> feat bit-identical.
__global__ __launch_bounds__(256) void conv_k(const float* __restrict__ X,
                                              const float* __restrict__ W,
                                              const float* __restrict__ B,
                                              float* __restrict__ F) {
  __shared__ double Xs[1280];   // [c8][4 rows][40 cols] (zero-padded halo)
  __shared__ double Ws[4608];   // [c8][9 taps][64 o]
  const int tid  = threadIdx.x;
  const int lane = tid & 63;
  const int wv   = tid >> 6;
  const int r_off = wv >> 1;          // 0..1
  const int seg   = (wv & 1) * 20;    // 0 or 20 (cols 20..39: last 2 px dummy)
  const int y0 = blockIdx.x * 2;
  const int o0 = blockIdx.y * 64;
  const int n  = blockIdx.z;
  const float* xn = X + ((size_t)n * 512) * HW;

  double acc[20];
#pragma unroll
  for (int p = 0; p < 20; ++p) acc[p] = 0.;

  for (int cc = 0; cc < 64; ++cc) {
    const int cb = cc * 8;
    // stage X tile: 8 c x 4 rows x 40 cols, zero-padded
#pragma unroll
    for (int u = 0; u < 5; ++u) {
      int e = tid + u * 256;
      int cl = e / 160, rem = e - cl * 160;
      int row = rem / 40, col = rem - row * 40;
      int iy = y0 - 1 + row, ix = col - 1;
      float v = 0.f;
      if (iy >= 0 && iy < 38 && ix >= 0 && ix < 38)
        v = xn[(size_t)(cb + cl) * HW + iy * 38 + ix];
      Xs[e] = (double)v;
    }
    // stage W tile: e = ol*72 + cl*9 + k  ->  Ws[cl][k][ol]
#pragma unroll
    for (int u = 0; u < 18; ++u) {
      int e = tid + u * 256;
      int ol = e / 72, rem = e - ol * 72;
      int cl = rem / 9, k = rem - cl * 9;
      float v = W[((size_t)(o0 + ol) * 512 + (size_t)(cb + cl)) * 9 + k];
      Ws[cl * 576 + k * 64 + ol] = (double)v;
    }
    __syncthreads();
#pragma unroll
    for (int cl = 0; cl < 8; ++cl) {
      double w9[9];
#pragma unroll
      for (int k = 0; k < 9; ++k) w9[k] = Ws[cl * 576 + k * 64 + lane];
#pragma unroll
      for (int ky = 0; ky < 3; ++ky) {
        const double* xrow = &Xs[cl * 160 + (r_off + ky) * 40 + seg]; // 16B-aligned
        double xr[22];
#pragma unroll
        for (int j = 0; j < 11; ++j) {
          double2 t2 = ((const double2*)xrow)[j];
          xr[2 * j] = t2.x; xr[2 * j + 1] = t2.y;
        }
#pragma unroll
        for (int kx = 0; kx < 3; ++kx) {
          double wvv = w9[ky * 3 + kx];
#pragma unroll
          for (int p = 0; p < 20; ++p)
            acc[p] = fma(wvv, xr[p + kx], acc[p]);
        }
      }
    }
    __syncthreads();
  }
  double bb = (double)B[o0 + lane];
  float* fp = F + ((size_t)(n * 512 + o0 + lane)) * HW + (y0 + r_off) * 38;
#pragma unroll
  for (int p = 0; p < 20; ++p) {
    int col = seg + p;
    if (col < 38) fp[col] = (float)fmax(acc[p] + bb, 0.0);
  }
}

// ------- 1x1 heads (fp64) + bias + layout transform + fp64 softmax fg -------
__global__ __launch_bounds__(256) void heads_k(const float* __restrict__ F,
                                               const float* __restrict__ Wt,
                                               const float* __restrict__ lb,
                                               const float* __restrict__ sb,
                                               float* __restrict__ out,
                                               double* __restrict__ fg) {
  __shared__ float sf[512 * 4];
  __shared__ double ssc[4][18];
  int n = blockIdx.y;
  int p0 = blockIdx.x * 4;
  int tid = threadIdx.x;
  const float* fn = F + ((size_t)n * 512) * HW;
  for (int e = tid; e < 2048; e += 256) {
    int c = e >> 2, pl = e & 3;
    sf[e] = fn[c * HW + p0 + pl];
  }
  __syncthreads();
  int pl = tid & 3, o = tid >> 2;
  double acc = 0.;
  if (o < 54) {
    for (int c = 0; c < 512; ++c)
      acc = fma((double)Wt[(c << 6) | o], (double)sf[(c << 2) | pl], acc);
  }
  int p = p0 + pl;
  if (o < 36) {
    acc += (double)lb[o];
    out[OFF_LOCS + ((size_t)n * NA + (size_t)p * 9 + (o >> 2)) * 4 + (o & 3)] = (float)acc;
  } else if (o < 54) {
    int oo = o - 36;
    acc += (double)sb[oo];
    out[OFF_SCORES + ((size_t)n * NA + (size_t)p * 9 + (oo >> 1)) * 2 + (oo & 1)] = (float)acc;
    ssc[pl][oo] = acc;
  }
  __syncthreads();
  if (tid < 36) {
    int pl2 = tid / 9, a = tid - pl2 * 9;
    double s0 = ssc[pl2][a * 2], s1 = ssc[pl2][a * 2 + 1];
    double mx = fmax(s0, s1);
    double e0 = exp(s0 - mx), e1 = exp(s1 - mx);
    fg[(size_t)n * NA + (size_t)(p0 + pl2) * 9 + a] = e1 / (e0 + e1);
  }
}

// ---------------- anchors -> d_out anchor section ---------------------------
__global__ __launch_bounds__(256) void anchor_k(float* __restrict__ out) {
  int i = blockIdx.x * 256 + threadIdx.x;
  if (i >= NA) return;
  int p = i / 9, a = i - p * 9;
  int ri = a / 3, si = a - ri * 3;
  double sr  = (ri == 0) ? 0.7071067811865476 : (ri == 1 ? 1.0 : 1.4142135623730951);
  double sri = (ri == 0) ? 1.4142135623730951 : (ri == 1 ? 1.0 : 0.7071067811865476);
  double hs = (double)(128 << si) * sr;   // 16*scale*sqrt(r)
  double wd = (double)(128 << si) * sri;  // 16*scale*sqrt(1/r)
  int py = p / 38, px = p - py * 38;
  float sx = (float)(px * 16), sy = (float)(py * 16);
  float x1 = (float)(8.0 - 0.5 * wd), y1 = (float)(8.0 - 0.5 * hs);
  float x2 = (float)(8.0 + 0.5 * wd), y2 = (float)(8.0 + 0.5 * hs);
  float* ap = out + OFF_ANCH + (size_t)i * 4;
  ap[0] = sx + x1; ap[1] = sy + y1; ap[2] = sx + x2; ap[3] = sy + y2;
}

// ---------------- decode boxes (fp64) + valid + sort keys -------------------
__global__ __launch_bounds__(256) void decode_k(const float* __restrict__ out,
                                                const double* __restrict__ fg,
                                                const int* __restrict__ ihp,
                                                const int* __restrict__ iwp,
                                                double* __restrict__ boxes,
                                                unsigned long long* __restrict__ keys) {
  int t = blockIdx.x * 256 + threadIdx.x;   // 4*16384 exactly
  int n = t >> 14, i = t & 16383;
  if (i >= NA) { keys[t] = ~0ULL; return; }
  const float* ap = out + OFF_ANCH + (size_t)i * 4;
  double ax1 = ap[0], ay1 = ap[1], ax2 = ap[2], ay2 = ap[3];
  double aw = ax2 - ax1, ah = ay2 - ay1;
  double acx = ax1 + 0.5 * aw, acy = ay1 + 0.5 * ah;
  const float* lp = out + OFF_LOCS + ((size_t)n * NA + i) * 4;
  double cx = (double)lp[0] * aw + acx, cy = (double)lp[1] * ah + acy;
  double bw = aw * exp((double)lp[2]), bh = ah * exp((double)lp[3]);
  double iwf = as_dim(iwp[0]), ihf = as_dim(ihp[0]);
  double x1 = fmin(fmax(cx - 0.5 * bw, 0.0), iwf);
  double y1 = fmin(fmax(cy - 0.5 * bh, 0.0), ihf);
  double x2 = fmin(fmax(cx + 0.5 * bw, 0.0), iwf);
  double y2 = fmin(fmax(cy + 0.5 * bh, 0.0), ihf);
  bool valid = ((x2 - x1) >= 16.0) && ((y2 - y1) >= 16.0);
  double* bp = boxes + ((size_t)n * NA + i) * 4;
  bp[0] = x1; bp[1] = y1; bp[2] = x2; bp[3] = y2;
  double sc = fg[(size_t)n * NA + i];
  unsigned long long u = (unsigned long long)__double_as_longlong(sc);
  u = (u >> 63) ? ~u : (u | 0x8000000000000000ULL);  // ascending-sortable
  unsigned long long inv = ~u;                       // descending
  if (!valid) inv = INVALID_KEY;
  keys[t] = (inv & ~0x3FFFULL) | (unsigned long long)i;  // 50-bit score + idx
}

// ---- sort phase A: per-8192-half in-LDS bitonic sort (half0 asc, half1 desc)
__global__ __launch_bounds__(1024) void sortA_k(unsigned long long* __restrict__ keys) {
  __shared__ unsigned long long s[8192];   // 64 KB
  const int half = blockIdx.x & 1;
  unsigned long long* g = keys + (((size_t)(blockIdx.x >> 1)) << 14) + ((size_t)half << 13);
  const int tid = threadIdx.x;
  for (int i = tid; i < 8192; i += 1024) s[i] = g[i];
  for (int size = 2; size <= 8192; size <<= 1) {
    for (int stride = size >> 1; stride > 0; stride >>= 1) {
      __syncthreads();
      for (int u = tid; u < 4096; u += 1024) {
        int lo = u & (stride - 1);
        int i1 = ((u - lo) << 1) | lo;
        int i2 = i1 + stride;
        bool up = (i1 & size) == 0;
        if (half) up = !up;   // upper half sorts descending
        unsigned long long a = s[i1], b = s[i2];
        if ((a > b) == up) { s[i1] = b; s[i2] = a; }
      }
    }
  }
  __syncthreads();
  for (int i = tid; i < 8192; i += 1024) g[i] = s[i];
}

// ---- sort phase B: single global stride-8192 compare-exchange (ascending) --
__global__ __launch_bounds__(256) void sortB_k(unsigned long long* __restrict__ keys) {
  int t = blockIdx.x * 256 + threadIdx.x;   // 4*8192
  int n = t >> 13, i = t & 8191;
  unsigned long long* g = keys + ((size_t)n << 14);
  unsigned long long a = g[i], b = g[i + 8192];
  if (a > b) { g[i] = b; g[i + 8192] = a; }
}

// ---- sort phase C: per-8192-half in-LDS bitonic merge (ascending) ----------
__global__ __launch_bounds__(1024) void sortC_k(unsigned long long* __restrict__ keys) {
  __shared__ unsigned long long s[8192];
  unsigned long long* g = keys + (((size_t)(blockIdx.x >> 1)) << 14) + ((size_t)(blockIdx.x & 1) << 13);
  const int tid = threadIdx.x;
  for (int i = tid; i < 8192; i += 1024) s[i] = g[i];
  for (int stride = 4096; stride > 0; stride >>= 1) {
    __syncthreads();
    for (int u = tid; u < 4096; u += 1024) {
      int lo = u & (stride - 1);
      int i1 = ((u - lo) << 1) | lo;
      int i2 = i1 + stride;
      unsigned long long a = s[i1], b = s[i2];
      if (a > b) { s[i1] = b; s[i2] = a; }
    }
  }
  __syncthreads();
  for (int i = tid; i < 8192; i += 1024) g[i] = s[i];
}

// ---------------- gather sorted top-3000 boxes + valid bit-words ------------
__global__ void gather_k(const unsigned long long* __restrict__ keys,
                         const double* __restrict__ boxes,
                         double* __restrict__ bsort,
                         unsigned long long* __restrict__ vw) {
  int n = blockIdx.y, w = blockIdx.x, l = threadIdx.x;  // 47 x 4 blocks, 64 thr
  int r = w * 64 + l;
  bool valid = false;
  if (r < NPRE) {
    unsigned long long kk = keys[((size_t)n << 14) + r];
    valid = kk < INVALID_KEY;
    unsigned idx = (unsigned)(kk & 0x3FFFULL);
    const double* bp = boxes + ((size_t)n * NA + idx) * 4;
    double* dp = bsort + ((size_t)n * NPRE + r) * 4;
    dp[0] = bp[0]; dp[1] = bp[1]; dp[2] = bp[2]; dp[3] = bp[3];
  }
  unsigned long long mask = __ballot(valid);
  if (l == 0) vw[n * NW + w] = mask;
}

// ------- suppression matrix (fp64 IoU): bit j set iff j>i && iou>0.7 --------
__global__ __launch_bounds__(256) void iou_k(const double* __restrict__ bsort,
                                             unsigned long long* __restrict__ sup) {
  int t = blockIdx.x * 256 + threadIdx.x;
  if (t >= 4 * NPRE * NW) return;
  int w = t % NW; int rest = t / NW; int i = rest % NPRE; int n = rest / NPRE;
  const double* bb = bsort + (size_t)n * NPRE * 4;
  double bix1 = bb[(size_t)i*4], biy1 = bb[(size_t)i*4+1];
  double bix2 = bb[(size_t)i*4+2], biy2 = bb[(size_t)i*4+3];
  double ai = (bix2 - bix1) * (biy2 - biy1);
  unsigned long long word = 0ULL;
  int j0 = w << 6;
  if (j0 + 63 > i) {
    int lmax = NPRE - j0; if (lmax > 64) lmax = 64;
    for (int l = 0; l < lmax; ++l) {
      int j = j0 + l;
      if (j <= i) continue;
      const double* bj = bb + (size_t)j * 4;
      double aj = (bj[2] - bj[0]) * (bj[3] - bj[1]);
      double xx1 = fmax(bix1, bj[0]), yy1 = fmax(biy1, bj[1]);
      double xx2 = fmin(bix2, bj[2]), yy2 = fmin(biy2, bj[3]);
      double inter = fmax(xx2 - xx1, 0.0) * fmax(yy2 - yy1, 0.0);
      double uni = ai + aj - inter;
      double iou = (uni > 0.0) ? inter / uni : 0.0;
      word |= (unsigned long long)(iou > 0.7) << l;
    }
  }
  sup[((size_t)n * NPRE + i) * NW + w] = word;
}

// ------- NMS: block-64 mask propagation (1 wave/batch) + emit rois ----------
__global__ void nms_k(const unsigned long long* __restrict__ sup,
                      const unsigned long long* __restrict__ vwp,
                      const double* __restrict__ bsort,
                      float* __restrict__ out) {
  int n = blockIdx.x; int l = threadIdx.x;   // 64 threads = 1 wave
  unsigned long long vw = (l < NW) ? vwp[n * NW + l] : 0ULL;
  unsigned long long remv = 0ULL, keepw = 0ULL;
  const unsigned long long* sbase = sup + (size_t)n * NPRE * NW;
  for (int b = 0; b < NW; ++b) {
    int gi = b * 64 + l;
    unsigned long long r = (gi < NPRE) ? sbase[(size_t)gi * NW + b] : 0ULL;
    unsigned long long kept = __shfl(vw & ~remv, b);
    // intra-block sequential resolve (kept/todo are wave-uniform)
    unsigned long long todo = kept;
    while (todo) {
      int i = __builtin_ctzll(todo);
      unsigned long long ri = __shfl(r, i);
      kept &= ~ri;
      todo &= todo - 1;
      todo &= ~ri;
    }
    if (l == b) keepw = kept;
    // propagate suppression of kept candidates to all later column-blocks
    unsigned long long m = kept;
    while (m) {
      int i = __builtin_ctzll(m);
      m &= m - 1;
      if (l < NW) remv |= sbase[(size_t)(b * 64 + i) * NW + l];
    }
  }
  unsigned long long keep = keepw;
  int cnt = __popcll(keep);
  int pre = cnt;
#pragma unroll
  for (int d = 1; d < 64; d <<= 1) {
    int tt = __shfl_up(pre, d);
    if (l >= d) pre += tt;
  }
  int nk = __shfl(pre, 63);
  int excl = pre - cnt;
  __shared__ float sbox[NPOST * 4];
  unsigned long long m2 = keep; int rank = excl;
  while (m2) {
    int b = __builtin_ctzll(m2);
    m2 &= m2 - 1;
    if (rank < NPOST) {
      int j = (l << 6) + b;
      const double* bj = bsort + ((size_t)n * NPRE + j) * 4;
      sbox[rank*4]   = (float)bj[0]; sbox[rank*4+1] = (float)bj[1];
      sbox[rank*4+2] = (float)bj[2]; sbox[rank*4+3] = (float)bj[3];
    }
    ++rank;
  }
  __syncthreads();
  if (nk == 0 && l == 0) {
    const double* b0 = bsort + (size_t)n * NPRE * 4;
    sbox[0] = (float)b0[0]; sbox[1] = (float)b0[1];
    sbox[2] = (float)b0[2]; sbox[3] = (float)b0[3];
  }
  __syncthreads();
  int nke = nk > 0 ? nk : 1;
  for (int r = l; r < NPOST; r += 64) {
    int src = r < nke ? r : r % nke;
    float4 b4 = *(float4*)(sbox + src * 4);
    *(float4*)(out + OFF_ROIS + ((size_t)n * NPOST + r) * 4) = b4;
    out[OFF_IDX + n * NPOST + r] = (float)n;
  }
}

extern "C" void kernel_launch(void* const* d_in, const int* in_sizes, int n_in,
                              void* d_out, int out_size, void* d_ws, size_t ws_size,
                              hipStream_t stream) {
  const float* X  = (const float*)d_in[0];
  const float* CW = (const float*)d_in[1];
  const float* CB = (const float*)d_in[2];
  const float* SW = (const float*)d_in[3];
  const float* SB = (const float*)d_in[4];
  const float* LW = (const float*)d_in[5];
  const float* LB = (const float*)d_in[6];
  const int*   IH = (const int*)d_in[7];
  const int*   IW = (const int*)d_in[8];
  float* out = (float*)d_out;
  char* ws = (char*)d_ws;

  // ws carve. sup OVERLAYS feat (feat dead after heads_k). Peak: 14,949,504 B.
  float* feat = (float*)(ws + 0);                                  // 11,829,248
  unsigned long long* sup  = (unsigned long long*)(ws + 0);        //  4,512,000 (overlay)
  float* Wt    = (float*)(ws + 11829248);                          //    131,072
  double* fg   = (double*)(ws + 11960320);                         //    415,872
  double* boxes= (double*)(ws + 12376192);                         //  1,663,488
  unsigned long long* keys = (unsigned long long*)(ws + 14039680); //    524,288
  double* bsort= (double*)(ws + 14563968);                         //    384,000
  unsigned long long* vw   = (unsigned long long*)(ws + 14947968); //      1,536

  hipLaunchKernelGGL(wt_k,     dim3(128),        dim3(256),  0, stream, LW, SW, Wt);
  hipLaunchKernelGGL(conv_k,   dim3(19, 8, 4),   dim3(256),  0, stream, X, CW, CB, feat);
  hipLaunchKernelGGL(heads_k,  dim3(361, 4),     dim3(256),  0, stream, feat, Wt, LB, SB, out, fg);
  hipLaunchKernelGGL(anchor_k, dim3(51),         dim3(256),  0, stream, out);
  hipLaunchKernelGGL(decode_k, dim3(256),        dim3(256),  0, stream, out, fg, IH, IW, boxes, keys);
  hipLaunchKernelGGL(sortA_k,  dim3(8),          dim3(1024), 0, stream, keys);
  hipLaunchKernelGGL(sortB_k,  dim3(128),        dim3(256),  0, stream, keys);
  hipLaunchKernelGGL(sortC_k,  dim3(8),          dim3(1024), 0, stream, keys);
  hipLaunchKernelGGL(gather_k, dim3(47, 4),      dim3(64),   0, stream, keys, boxes, bsort, vw);
  hipLaunchKernelGGL(iou_k,    dim3((4*NPRE*NW + 255) / 256), dim3(256), 0, stream, bsort, sup);
  hipLaunchKernelGGL(nms_k,    dim3(4),          dim3(64),   0, stream, sup, vw, bsort, out);
}

// Round 5
// 1416.374 us; speedup vs baseline: 2.1553x; 1.3085x over previous
//
#include <hip/hip_runtime.h>
#include <cstdint>
#include <cstddef>

#define HW    1444      // 38*38
#define NA    12996     // HW*9
#define NPRE  3000
#define NW    47        // ceil(3000/64)
#define NPOST 300

// d_out section offsets (in floats)
#define OFF_LOCS   0         // 4*12996*4 = 207936
#define OFF_SCORES 207936    // 4*12996*2 = 103968
#define OFF_ROIS   311904    // 1200*4    = 4800
#define OFF_IDX    316704    // 4*300     = 1200
#define OFF_ANCH   317904    // 12996*4   = 51984

#define INVALID_KEY 0xFFF0000000000000ULL

__device__ inline double as_dim(int raw) {
  if (raw > 0 && raw < 1000000) return (double)raw;
  return (double)__int_as_float(raw);
}

// ---------------- W transpose: Wt[c*64 + o], o<36 loc, 36..53 score ----------
__global__ __launch_bounds__(256) void wt_k(const float* __restrict__ lw,
                                            const float* __restrict__ sw,
                                            float* __restrict__ Wt) {
  int t = blockIdx.x * 256 + threadIdx.x;
  if (t >= 64 * 512) return;
  int o = t & 63, c = t >> 6;
  float v = 0.f;
  if (o < 36)      v = lw[o * 512 + c];
  else if (o < 54) v = sw[(o - 36) * 512 + c];
  Wt[t] = v;
}

// ------- 3x3 conv, f64 acc, LDS-tiled: lanes=64 o, 20 px/thread -------------
// Xs: f64 (reads are wave-uniform broadcasts -> conflict-free).
// Wsf: f32 padded o-dim 65 -> stride-65 writes & stride-1 reads conflict-free;
//      cvt f32->f64 in reg is exact, so FMA values+order == R4 -> feat bit-id.
// Global staging software-pipelined (prefetch regs for cc+1 during compute cc).
__global__ __launch_bounds__(256) void conv_k(const float* __restrict__ X,
                                              const float* __restrict__ W,
                                              const float* __restrict__ B,
                                              float* __restrict__ F) {
  __shared__ double Xs[1280];      // [c8][4 rows][40 cols] f64, 10240 B
  __shared__ float  Wsf[4680];     // [c8*9taps][65 o-pad] f32, 18720 B
  const int tid  = threadIdx.x;
  const int lane = tid & 63;
  const int wv   = tid >> 6;
  const int r_off = wv >> 1;          // 0..1
  const int seg   = (wv & 1) * 20;    // 0 or 20 (cols 20..39: last 2 px dummy)
  const int y0 = blockIdx.x * 2;
  const int o0 = blockIdx.y * 64;
  const int n  = blockIdx.z;
  const float* xn = X + ((size_t)n * 512) * HW;

  // loop-invariant staging descriptors
  int xsrc[5]; bool xval[5];
#pragma unroll
  for (int u = 0; u < 5; ++u) {
    int e = tid + u * 256;
    int cl = e / 160, rem = e - cl * 160;
    int row = rem / 40, col = rem - row * 40;
    int iy = y0 - 1 + row, ix = col - 1;
    xval[u] = (iy >= 0 && iy < 38 && ix >= 0 && ix < 38);
    xsrc[u] = cl * HW + (xval[u] ? iy * 38 + ix : 0);
  }
  int wdst[18], wsrc[18];
#pragma unroll
  for (int u = 0; u < 18; ++u) {
    int e = tid + u * 256;
    int ol = e / 72, rem = e - ol * 72;
    int cl = rem / 9, k = rem - cl * 9;
    wdst[u] = (cl * 9 + k) * 65 + ol;
    wsrc[u] = (o0 + ol) * 4608 + cl * 9 + k;
  }

  float xr_[5], wr_[18];
#pragma unroll
  for (int u = 0; u < 5; ++u)  xr_[u] = xval[u] ? xn[xsrc[u]] : 0.f;
#pragma unroll
  for (int u = 0; u < 18; ++u) wr_[u] = W[wsrc[u]];

  double acc[20];
#pragma unroll
  for (int p = 0; p < 20; ++p) acc[p] = 0.;

  for (int cc = 0; cc < 64; ++cc) {
    __syncthreads();
#pragma unroll
    for (int u = 0; u < 5; ++u)  Xs[tid + u * 256] = (double)xr_[u];
#pragma unroll
    for (int u = 0; u < 18; ++u) Wsf[wdst[u]] = wr_[u];
    __syncthreads();
    if (cc < 63) {
      const int cb = (cc + 1) * 8;
#pragma unroll
      for (int u = 0; u < 5; ++u)  xr_[u] = xval[u] ? xn[(size_t)cb * HW + xsrc[u]] : 0.f;
#pragma unroll
      for (int u = 0; u < 18; ++u) wr_[u] = W[wsrc[u] + cb * 9];
    }
#pragma unroll
    for (int cl = 0; cl < 8; ++cl) {
      double w9[9];
#pragma unroll
      for (int k = 0; k < 9; ++k) w9[k] = (double)Wsf[(cl * 9 + k) * 65 + lane];
#pragma unroll
      for (int ky = 0; ky < 3; ++ky) {
        const double* xrow = &Xs[cl * 160 + (r_off + ky) * 40 + seg]; // 16B-aligned
        double xr[22];
#pragma unroll
        for (int j = 0; j < 11; ++j) {
          double2 t2 = ((const double2*)xrow)[j];
          xr[2 * j] = t2.x; xr[2 * j + 1] = t2.y;
        }
#pragma unroll
        for (int kx = 0; kx < 3; ++kx) {
          double wvv = w9[ky * 3 + kx];
#pragma unroll
          for (int p = 0; p < 20; ++p)
            acc[p] = fma(wvv, xr[p + kx], acc[p]);
        }
      }
    }
  }
  double bb = (double)B[o0 + lane];
  float* fp = F + ((size_t)(n * 512 + o0 + lane)) * HW + (y0 + r_off) * 38;
#pragma unroll
  for (int p = 0; p < 20; ++p) {
    int col = seg + p;
    if (col < 38) fp[col] = (float)fmax(acc[p] + bb, 0.0);
  }
}

// ------- 1x1 heads (fp64) + bias + layout transform + fp64 softmax fg -------
__global__ __launch_bounds__(256) void heads_k(const float* __restrict__ F,
                                               const float* __restrict__ Wt,
                                               const float* __restrict__ lb,
                                               const float* __restrict__ sb,
                                               float* __restrict__ out,
                                               double* __restrict__ fg) {
  __shared__ float sf[512 * 4];
  __shared__ double ssc[4][18];
  int n = blockIdx.y;
  int p0 = blockIdx.x * 4;
  int tid = threadIdx.x;
  const float* fn = F + ((size_t)n * 512) * HW;
  for (int e = tid; e < 2048; e += 256) {
    int c = e >> 2, pl = e & 3;
    sf[e] = fn[c * HW + p0 + pl];
  }
  __syncthreads();
  int pl = tid & 3, o = tid >> 2;
  double acc = 0.;
  if (o < 54) {
    for (int c = 0; c < 512; ++c)
      acc = fma((double)Wt[(c << 6) | o], (double)sf[(c << 2) | pl], acc);
  }
  int p = p0 + pl;
  if (o < 36) {
    acc += (double)lb[o];
    out[OFF_LOCS + ((size_t)n * NA + (size_t)p * 9 + (o >> 2)) * 4 + (o & 3)] = (float)acc;
  } else if (o < 54) {
    int oo = o - 36;
    acc += (double)sb[oo];
    out[OFF_SCORES + ((size_t)n * NA + (size_t)p * 9 + (oo >> 1)) * 2 + (oo & 1)] = (float)acc;
    ssc[pl][oo] = acc;
  }
  __syncthreads();
  if (tid < 36) {
    int pl2 = tid / 9, a = tid - pl2 * 9;
    double s0 = ssc[pl2][a * 2], s1 = ssc[pl2][a * 2 + 1];
    double mx = fmax(s0, s1);
    double e0 = exp(s0 - mx), e1 = exp(s1 - mx);
    fg[(size_t)n * NA + (size_t)(p0 + pl2) * 9 + a] = e1 / (e0 + e1);
  }
}

// ---------------- anchors -> d_out anchor section ---------------------------
__global__ __launch_bounds__(256) void anchor_k(float* __restrict__ out) {
  int i = blockIdx.x * 256 + threadIdx.x;
  if (i >= NA) return;
  int p = i / 9, a = i - p * 9;
  int ri = a / 3, si = a - ri * 3;
  double sr  = (ri == 0) ? 0.7071067811865476 : (ri == 1 ? 1.0 : 1.4142135623730951);
  double sri = (ri == 0) ? 1.4142135623730951 : (ri == 1 ? 1.0 : 0.7071067811865476);
  double hs = (double)(128 << si) * sr;   // 16*scale*sqrt(r)
  double wd = (double)(128 << si) * sri;  // 16*scale*sqrt(1/r)
  int py = p / 38, px = p - py * 38;
  float sx = (float)(px * 16), sy = (float)(py * 16);
  float x1 = (float)(8.0 - 0.5 * wd), y1 = (float)(8.0 - 0.5 * hs);
  float x2 = (float)(8.0 + 0.5 * wd), y2 = (float)(8.0 + 0.5 * hs);
  float* ap = out + OFF_ANCH + (size_t)i * 4;
  ap[0] = sx + x1; ap[1] = sy + y1; ap[2] = sx + x2; ap[3] = sy + y2;
}

// ---------------- decode boxes (fp64) + valid + sort keys -------------------
__global__ __launch_bounds__(256) void decode_k(const float* __restrict__ out,
                                                const double* __restrict__ fg,
                                                const int* __restrict__ ihp,
                                                const int* __restrict__ iwp,
                                                double* __restrict__ boxes,
                                                unsigned long long* __restrict__ keys) {
  int t = blockIdx.x * 256 + threadIdx.x;   // 4*16384 exactly
  int n = t >> 14, i = t & 16383;
  if (i >= NA) { keys[t] = ~0ULL; return; }
  const float* ap = out + OFF_ANCH + (size_t)i * 4;
  double ax1 = ap[0], ay1 = ap[1], ax2 = ap[2], ay2 = ap[3];
  double aw = ax2 - ax1, ah = ay2 - ay1;
  double acx = ax1 + 0.5 * aw, acy = ay1 + 0.5 * ah;
  const float* lp = out + OFF_LOCS + ((size_t)n * NA + i) * 4;
  double cx = (double)lp[0] * aw + acx, cy = (double)lp[1] * ah + acy;
  double bw = aw * exp((double)lp[2]), bh = ah * exp((double)lp[3]);
  double iwf = as_dim(iwp[0]), ihf = as_dim(ihp[0]);
  double x1 = fmin(fmax(cx - 0.5 * bw, 0.0), iwf);
  double y1 = fmin(fmax(cy - 0.5 * bh, 0.0), ihf);
  double x2 = fmin(fmax(cx + 0.5 * bw, 0.0), iwf);
  double y2 = fmin(fmax(cy + 0.5 * bh, 0.0), ihf);
  bool valid = ((x2 - x1) >= 16.0) && ((y2 - y1) >= 16.0);
  double* bp = boxes + ((size_t)n * NA + i) * 4;
  bp[0] = x1; bp[1] = y1; bp[2] = x2; bp[3] = y2;
  double sc = fg[(size_t)n * NA + i];
  unsigned long long u = (unsigned long long)__double_as_longlong(sc);
  u = (u >> 63) ? ~u : (u | 0x8000000000000000ULL);  // ascending-sortable
  unsigned long long inv = ~u;                       // descending
  if (!valid) inv = INVALID_KEY;
  keys[t] = (inv & ~0x3FFFULL) | (unsigned long long)i;  // 50-bit score + idx
}

// ---- sort phase A: per-8192-half in-LDS bitonic sort (half0 asc, half1 desc)
__global__ __launch_bounds__(1024) void sortA_k(unsigned long long* __restrict__ keys) {
  __shared__ unsigned long long s[8192];   // 64 KB
  const int half = blockIdx.x & 1;
  unsigned long long* g = keys + (((size_t)(blockIdx.x >> 1)) << 14) + ((size_t)half << 13);
  const int tid = threadIdx.x;
  for (int i = tid; i < 8192; i += 1024) s[i] = g[i];
  for (int size = 2; size <= 8192; size <<= 1) {
    for (int stride = size >> 1; stride > 0; stride >>= 1) {
      __syncthreads();
      for (int u = tid; u < 4096; u += 1024) {
        int lo = u & (stride - 1);
        int i1 = ((u - lo) << 1) | lo;
        int i2 = i1 + stride;
        bool up = (i1 & size) == 0;
        if (half) up = !up;   // upper half sorts descending
        unsigned long long a = s[i1], b = s[i2];
        if ((a > b) == up) { s[i1] = b; s[i2] = a; }
      }
    }
  }
  __syncthreads();
  for (int i = tid; i < 8192; i += 1024) g[i] = s[i];
}

// ---- sort phase B: single global stride-8192 compare-exchange (ascending) --
__global__ __launch_bounds__(256) void sortB_k(unsigned long long* __restrict__ keys) {
  int t = blockIdx.x * 256 + threadIdx.x;   // 4*8192
  int n = t >> 13, i = t & 8191;
  unsigned long long* g = keys + ((size_t)n << 14);
  unsigned long long a = g[i], b = g[i + 8192];
  if (a > b) { g[i] = b; g[i + 8192] = a; }
}

// ---- sort phase C: per-8192-half in-LDS bitonic merge (ascending) ----------
__global__ __launch_bounds__(1024) void sortC_k(unsigned long long* __restrict__ keys) {
  __shared__ unsigned long long s[8192];
  unsigned long long* g = keys + (((size_t)(blockIdx.x >> 1)) << 14) + ((size_t)(blockIdx.x & 1) << 13);
  const int tid = threadIdx.x;
  for (int i = tid; i < 8192; i += 1024) s[i] = g[i];
  for (int stride = 4096; stride > 0; stride >>= 1) {
    __syncthreads();
    for (int u = tid; u < 4096; u += 1024) {
      int lo = u & (stride - 1);
      int i1 = ((u - lo) << 1) | lo;
      int i2 = i1 + stride;
      unsigned long long a = s[i1], b = s[i2];
      if (a > b) { s[i1] = b; s[i2] = a; }
    }
  }
  __syncthreads();
  for (int i = tid; i < 8192; i += 1024) g[i] = s[i];
}

// ---------------- gather sorted top-3000 boxes + valid bit-words ------------
__global__ void gather_k(const unsigned long long* __restrict__ keys,
                         const double* __restrict__ boxes,
                         double* __restrict__ bsort,
                         unsigned long long* __restrict__ vw) {
  int n = blockIdx.y, w = blockIdx.x, l = threadIdx.x;  // 47 x 4 blocks, 64 thr
  int r = w * 64 + l;
  bool valid = false;
  if (r < NPRE) {
    unsigned long long kk = keys[((size_t)n << 14) + r];
    valid = kk < INVALID_KEY;
    unsigned idx = (unsigned)(kk & 0x3FFFULL);
    const double* bp = boxes + ((size_t)n * NA + idx) * 4;
    double* dp = bsort + ((size_t)n * NPRE + r) * 4;
    dp[0] = bp[0]; dp[1] = bp[1]; dp[2] = bp[2]; dp[3] = bp[3];
  }
  unsigned long long mask = __ballot(valid);
  if (l == 0) vw[n * NW + w] = mask;
}

// ------- suppression matrix (fp64 IoU): bit j set iff j>i && iou>0.7 --------
__global__ __launch_bounds__(256) void iou_k(const double* __restrict__ bsort,
                                             unsigned long long* __restrict__ sup) {
  int t = blockIdx.x * 256 + threadIdx.x;
  if (t >= 4 * NPRE * NW) return;
  int w = t % NW; int rest = t / NW; int i = rest % NPRE; int n = rest / NPRE;
  const double* bb = bsort + (size_t)n * NPRE * 4;
  double bix1 = bb[(size_t)i*4], biy1 = bb[(size_t)i*4+1];
  double bix2 = bb[(size_t)i*4+2], biy2 = bb[(size_t)i*4+3];
  double ai = (bix2 - bix1) * (biy2 - biy1);
  unsigned long long word = 0ULL;
  int j0 = w << 6;
  if (j0 + 63 > i) {
    int lmax = NPRE - j0; if (lmax > 64) lmax = 64;
    for (int l = 0; l < lmax; ++l) {
      int j = j0 + l;
      if (j <= i) continue;
      const double* bj = bb + (size_t)j * 4;
      double aj = (bj[2] - bj[0]) * (bj[3] - bj[1]);
      double xx1 = fmax(bix1, bj[0]), yy1 = fmax(biy1, bj[1]);
      double xx2 = fmin(bix2, bj[2]), yy2 = fmin(biy2, bj[3]);
      double inter = fmax(xx2 - xx1, 0.0) * fmax(yy2 - yy1, 0.0);
      double uni = ai + aj - inter;
      double iou = (uni > 0.0) ? inter / uni : 0.0;
      word |= (unsigned long long)(iou > 0.7) << l;
    }
  }
  sup[((size_t)n * NPRE + i) * NW + w] = word;
}

// ------- NMS: block-64 mask propagation (1 wave/batch) + emit rois ----------
__global__ void nms_k(const unsigned long long* __restrict__ sup,
                      const unsigned long long* __restrict__ vwp,
                      const double* __restrict__ bsort,
                      float* __restrict__ out) {
  int n = blockIdx.x; int l = threadIdx.x;   // 64 threads = 1 wave
  unsigned long long vw = (l < NW) ? vwp[n * NW + l] : 0ULL;
  unsigned long long remv = 0ULL, keepw = 0ULL;
  const unsigned long long* sbase = sup + (size_t)n * NPRE * NW;
  for (int b = 0; b < NW; ++b) {
    int gi = b * 64 + l;
    unsigned long long r = (gi < NPRE) ? sbase[(size_t)gi * NW + b] : 0ULL;
    unsigned long long kept = __shfl(vw & ~remv, b);
    // intra-block sequential resolve (kept/todo are wave-uniform)
    unsigned long long todo = kept;
    while (todo) {
      int i = __builtin_ctzll(todo);
      unsigned long long ri = __shfl(r, i);
      kept &= ~ri;
      todo &= todo - 1;
      todo &= ~ri;
    }
    if (l == b) keepw = kept;
    // propagate suppression of kept candidates to all later column-blocks
    unsigned long long m = kept;
    while (m) {
      int i = __builtin_ctzll(m);
      m &= m - 1;
      if (l < NW) remv |= sbase[(size_t)(b * 64 + i) * NW + l];
    }
  }
  unsigned long long keep = keepw;
  int cnt = __popcll(keep);
  int pre = cnt;
#pragma unroll
  for (int d = 1; d < 64; d <<= 1) {
    int tt = __shfl_up(pre, d);
    if (l >= d) pre += tt;
  }
  int nk = __shfl(pre, 63);
  int excl = pre - cnt;
  __shared__ float sbox[NPOST * 4];
  unsigned long long m2 = keep; int rank = excl;
  while (m2) {
    int b = __builtin_ctzll(m2);
    m2 &= m2 - 1;
    if (rank < NPOST) {
      int j = (l << 6) + b;
      const double* bj = bsort + ((size_t)n * NPRE + j) * 4;
      sbox[rank*4]   = (float)bj[0]; sbox[rank*4+1] = (float)bj[1];
      sbox[rank*4+2] = (float)bj[2]; sbox[rank*4+3] = (float)bj[3];
    }
    ++rank;
  }
  __syncthreads();
  if (nk == 0 && l == 0) {
    const double* b0 = bsort + (size_t)n * NPRE * 4;
    sbox[0] = (float)b0[0]; sbox[1] = (float)b0[1];
    sbox[2] = (float)b0[2]; sbox[3] = (float)b0[3];
  }
  __syncthreads();
  int nke = nk > 0 ? nk : 1;
  for (int r = l; r < NPOST; r += 64) {
    int src = r < nke ? r : r % nke;
    float4 b4 = *(float4*)(sbox + src * 4);
    *(float4*)(out + OFF_ROIS + ((size_t)n * NPOST + r) * 4) = b4;
    out[OFF_IDX + n * NPOST + r] = (float)n;
  }
}

extern "C" void kernel_launch(void* const* d_in, const int* in_sizes, int n_in,
                              void* d_out, int out_size, void* d_ws, size_t ws_size,
                              hipStream_t stream) {
  const float* X  = (const float*)d_in[0];
  const float* CW = (const float*)d_in[1];
  const float* CB = (const float*)d_in[2];
  const float* SW = (const float*)d_in[3];
  const float* SB = (const float*)d_in[4];
  const float* LW = (const float*)d_in[5];
  const float* LB = (const float*)d_in[6];
  const int*   IH = (const int*)d_in[7];
  const int*   IW = (const int*)d_in[8];
  float* out = (float*)d_out;
  char* ws = (char*)d_ws;

  // ws carve. sup OVERLAYS feat (feat dead after heads_k). Peak: 14,949,504 B.
  float* feat = (float*)(ws + 0);                                  // 11,829,248
  unsigned long long* sup  = (unsigned long long*)(ws + 0);        //  4,512,000 (overlay)
  float* Wt    = (float*)(ws + 11829248);                          //    131,072
  double* fg   = (double*)(ws + 11960320);                         //    415,872
  double* boxes= (double*)(ws + 12376192);                         //  1,663,488
  unsigned long long* keys = (unsigned long long*)(ws + 14039680); //    524,288
  double* bsort= (double*)(ws + 14563968);                         //    384,000
  unsigned long long* vw   = (unsigned long long*)(ws + 14947968); //      1,536

  hipLaunchKernelGGL(wt_k,     dim3(128),        dim3(256),  0, stream, LW, SW, Wt);
  hipLaunchKernelGGL(conv_k,   dim3(19, 8, 4),   dim3(256),  0, stream, X, CW, CB, feat);
  hipLaunchKernelGGL(heads_k,  dim3(361, 4),     dim3(256),  0, stream, feat, Wt, LB, SB, out, fg);
  hipLaunchKernelGGL(anchor_k, dim3(51),         dim3(256),  0, stream, out);
  hipLaunchKernelGGL(decode_k, dim3(256),        dim3(256),  0, stream, out, fg, IH, IW, boxes, keys);
  hipLaunchKernelGGL(sortA_k,  dim3(8),          dim3(1024), 0, stream, keys);
  hipLaunchKernelGGL(sortB_k,  dim3(128),        dim3(256),  0, stream, keys);
  hipLaunchKernelGGL(sortC_k,  dim3(8),          dim3(1024), 0, stream, keys);
  hipLaunchKernelGGL(gather_k, dim3(47, 4),      dim3(64),   0, stream, keys, boxes, bsort, vw);
  hipLaunchKernelGGL(iou_k,    dim3((4*NPRE*NW + 255) / 256), dim3(256), 0, stream, bsort, sup);
  hipLaunchKernelGGL(nms_k,    dim3(4),          dim3(64),   0, stream, sup, vw, bsort, out);
}

// Round 6
// 1400.763 us; speedup vs baseline: 2.1793x; 1.0111x over previous
//
#include <hip/hip_runtime.h>
#include <cstdint>
#include <cstddef>

#define HW    1444      // 38*38
#define NA    12996     // HW*9
#define NPRE  3000
#define NW    47        // ceil(3000/64)
#define NPOST 300

// d_out section offsets (in floats)
#define OFF_LOCS   0         // 4*12996*4 = 207936
#define OFF_SCORES 207936    // 4*12996*2 = 103968
#define OFF_ROIS   311904    // 1200*4    = 4800
#define OFF_IDX    316704    // 4*300     = 1200
#define OFF_ANCH   317904    // 12996*4   = 51984

#define INVALID_KEY 0xFFF0000000000000ULL

__device__ inline double as_dim(int raw) {
  if (raw > 0 && raw < 1000000) return (double)raw;
  return (double)__int_as_float(raw);
}

// ---------------- W transpose: Wt[c*64 + o], o<36 loc, 36..53 score ----------
__global__ __launch_bounds__(256) void wt_k(const float* __restrict__ lw,
                                            const float* __restrict__ sw,
                                            float* __restrict__ Wt) {
  int t = blockIdx.x * 256 + threadIdx.x;
  if (t >= 64 * 512) return;
  int o = t & 63, c = t >> 6;
  float v = 0.f;
  if (o < 36)      v = lw[o * 512 + c];
  else if (o < 54) v = sw[(o - 36) * 512 + c];
  Wt[t] = v;
}

// ------- 3x3 conv, f64 acc, LDS-tiled: 1 row/block, lanes=64 o --------------
// grid (38,8,4) = 1216 blocks -> ~4.75 blocks/CU (occupancy fix vs R5's 608).
// Per-pixel sum order (c asc, cl asc, ky,kx asc) identical to R5 -> feat
// bit-identical -> selection untouched.
// Xs f64 reads are wave-uniform broadcasts; Wsf f32 lane-stride-1 (2-way free);
// staging writes conflict-free (Xs 2-way pairs, Wsf stride-65).
__global__ __launch_bounds__(256) void conv_k(const float* __restrict__ X,
                                              const float* __restrict__ W,
                                              const float* __restrict__ B,
                                              float* __restrict__ F) {
  __shared__ double Xs[960];       // [c8][3 rows][40 cols] f64, 7680 B
  __shared__ float  Wsf[4680];     // [c8*9taps][65 o-pad] f32, 18720 B
  const int tid  = threadIdx.x;
  const int lane = tid & 63;
  const int wv   = tid >> 6;
  const int seg  = wv * 10;        // cols seg..seg+9 (wave 3: 30..37 + 2 dummy)
  const int y  = blockIdx.x;
  const int o0 = blockIdx.y * 64;
  const int n  = blockIdx.z;
  const float* xn = X + ((size_t)n * 512) * HW;

  // loop-invariant staging descriptors
  int xsrc[4]; bool xval[4]; bool xact[4];
#pragma unroll
  for (int u = 0; u < 4; ++u) {
    int e = tid + u * 256;
    xact[u] = (e < 960);
    int cl = e / 120, rem = e - cl * 120;
    int row = rem / 40, col = rem - row * 40;
    int iy = y - 1 + row, ix = col - 1;
    xval[u] = xact[u] && (iy >= 0 && iy < 38 && ix >= 0 && ix < 38);
    xsrc[u] = xval[u] ? (cl * HW + iy * 38 + ix) : 0;
  }
  int wdst[18], wsrc[18];
#pragma unroll
  for (int u = 0; u < 18; ++u) {
    int e = tid + u * 256;
    int ol = e / 72, rem = e - ol * 72;
    int cl = rem / 9, k = rem - cl * 9;
    wdst[u] = (cl * 9 + k) * 65 + ol;
    wsrc[u] = (o0 + ol) * 4608 + cl * 9 + k;
  }

  float xr_[4], wr_[18];
#pragma unroll
  for (int u = 0; u < 4; ++u)  xr_[u] = xval[u] ? xn[xsrc[u]] : 0.f;
#pragma unroll
  for (int u = 0; u < 18; ++u) wr_[u] = W[wsrc[u]];

  double acc[10];
#pragma unroll
  for (int p = 0; p < 10; ++p) acc[p] = 0.;

  for (int cc = 0; cc < 64; ++cc) {
    __syncthreads();
#pragma unroll
    for (int u = 0; u < 4; ++u)
      if (xact[u]) Xs[tid + u * 256] = (double)xr_[u];
#pragma unroll
    for (int u = 0; u < 18; ++u) Wsf[wdst[u]] = wr_[u];
    __syncthreads();
    if (cc < 63) {
      const int cb = (cc + 1) * 8;
#pragma unroll
      for (int u = 0; u < 4; ++u)  xr_[u] = xval[u] ? xn[(size_t)cb * HW + xsrc[u]] : 0.f;
#pragma unroll
      for (int u = 0; u < 18; ++u) wr_[u] = W[wsrc[u] + cb * 9];
    }
#pragma unroll
    for (int cl = 0; cl < 8; ++cl) {
      double w9[9];
#pragma unroll
      for (int k = 0; k < 9; ++k) w9[k] = (double)Wsf[(cl * 9 + k) * 65 + lane];
#pragma unroll
      for (int ky = 0; ky < 3; ++ky) {
        const double* xrow = &Xs[cl * 120 + ky * 40 + seg]; // 16B-aligned
        double xr[12];
#pragma unroll
        for (int j = 0; j < 6; ++j) {
          double2 t2 = ((const double2*)xrow)[j];
          xr[2 * j] = t2.x; xr[2 * j + 1] = t2.y;
        }
#pragma unroll
        for (int kx = 0; kx < 3; ++kx) {
          double wvv = w9[ky * 3 + kx];
#pragma unroll
          for (int p = 0; p < 10; ++p)
            acc[p] = fma(wvv, xr[p + kx], acc[p]);
        }
      }
    }
  }
  double bb = (double)B[o0 + lane];
  float* fp = F + ((size_t)(n * 512 + o0 + lane)) * HW + y * 38;
#pragma unroll
  for (int p = 0; p < 10; ++p) {
    int col = seg + p;
    if (col < 38) fp[col] = (float)fmax(acc[p] + bb, 0.0);
  }
}

// ------- 1x1 heads (fp64) + bias + layout transform + fp64 softmax fg -------
__global__ __launch_bounds__(256) void heads_k(const float* __restrict__ F,
                                               const float* __restrict__ Wt,
                                               const float* __restrict__ lb,
                                               const float* __restrict__ sb,
                                               float* __restrict__ out,
                                               double* __restrict__ fg) {
  __shared__ float sf[512 * 4];
  __shared__ double ssc[4][18];
  int n = blockIdx.y;
  int p0 = blockIdx.x * 4;
  int tid = threadIdx.x;
  const float* fn = F + ((size_t)n * 512) * HW;
  for (int e = tid; e < 2048; e += 256) {
    int c = e >> 2, pl = e & 3;
    sf[e] = fn[c * HW + p0 + pl];
  }
  __syncthreads();
  int pl = tid & 3, o = tid >> 2;
  double acc = 0.;
  if (o < 54) {
    for (int c = 0; c < 512; ++c)
      acc = fma((double)Wt[(c << 6) | o], (double)sf[(c << 2) | pl], acc);
  }
  int p = p0 + pl;
  if (o < 36) {
    acc += (double)lb[o];
    out[OFF_LOCS + ((size_t)n * NA + (size_t)p * 9 + (o >> 2)) * 4 + (o & 3)] = (float)acc;
  } else if (o < 54) {
    int oo = o - 36;
    acc += (double)sb[oo];
    out[OFF_SCORES + ((size_t)n * NA + (size_t)p * 9 + (oo >> 1)) * 2 + (oo & 1)] = (float)acc;
    ssc[pl][oo] = acc;
  }
  __syncthreads();
  if (tid < 36) {
    int pl2 = tid / 9, a = tid - pl2 * 9;
    double s0 = ssc[pl2][a * 2], s1 = ssc[pl2][a * 2 + 1];
    double mx = fmax(s0, s1);
    double e0 = exp(s0 - mx), e1 = exp(s1 - mx);
    fg[(size_t)n * NA + (size_t)(p0 + pl2) * 9 + a] = e1 / (e0 + e1);
  }
}

// ------ decode boxes (fp64) + inline anchors + valid + sort keys ------------
// anchor computed inline with the exact float-rounding sequence of old
// anchor_k; written to d_out anchors section by the n==0 slice.
__global__ __launch_bounds__(256) void decode_k(const float* __restrict__ out_c,
                                                float* __restrict__ out,
                                                const double* __restrict__ fg,
                                                const int* __restrict__ ihp,
                                                const int* __restrict__ iwp,
                                                double* __restrict__ boxes,
                                                unsigned long long* __restrict__ keys) {
  int t = blockIdx.x * 256 + threadIdx.x;   // 4*16384 exactly
  int n = t >> 14, i = t & 16383;
  if (i >= NA) { keys[t] = ~0ULL; return; }
  int p = i / 9, a = i - p * 9;
  int ri = a / 3, si = a - ri * 3;
  double sr  = (ri == 0) ? 0.7071067811865476 : (ri == 1 ? 1.0 : 1.4142135623730951);
  double sri = (ri == 0) ? 1.4142135623730951 : (ri == 1 ? 1.0 : 0.7071067811865476);
  double hs = (double)(128 << si) * sr;
  double wd = (double)(128 << si) * sri;
  int py = p / 38, px = p - py * 38;
  float sx = (float)(px * 16), sy = (float)(py * 16);
  float fx1 = (float)(8.0 - 0.5 * wd), fy1 = (float)(8.0 - 0.5 * hs);
  float fx2 = (float)(8.0 + 0.5 * wd), fy2 = (float)(8.0 + 0.5 * hs);
  float ax1f = sx + fx1, ay1f = sy + fy1, ax2f = sx + fx2, ay2f = sy + fy2;
  if (n == 0) {
    float* ap = out + OFF_ANCH + (size_t)i * 4;
    ap[0] = ax1f; ap[1] = ay1f; ap[2] = ax2f; ap[3] = ay2f;
  }
  double ax1 = ax1f, ay1 = ay1f, ax2 = ax2f, ay2 = ay2f;
  double aw = ax2 - ax1, ah = ay2 - ay1;
  double acx = ax1 + 0.5 * aw, acy = ay1 + 0.5 * ah;
  const float* lp = out_c + OFF_LOCS + ((size_t)n * NA + i) * 4;
  double cx = (double)lp[0] * aw + acx, cy = (double)lp[1] * ah + acy;
  double bw = aw * exp((double)lp[2]), bh = ah * exp((double)lp[3]);
  double iwf = as_dim(iwp[0]), ihf = as_dim(ihp[0]);
  double x1 = fmin(fmax(cx - 0.5 * bw, 0.0), iwf);
  double y1 = fmin(fmax(cy - 0.5 * bh, 0.0), ihf);
  double x2 = fmin(fmax(cx + 0.5 * bw, 0.0), iwf);
  double y2 = fmin(fmax(cy + 0.5 * bh, 0.0), ihf);
  bool valid = ((x2 - x1) >= 16.0) && ((y2 - y1) >= 16.0);
  double* bp = boxes + ((size_t)n * NA + i) * 4;
  bp[0] = x1; bp[1] = y1; bp[2] = x2; bp[3] = y2;
  double sc = fg[(size_t)n * NA + i];
  unsigned long long u = (unsigned long long)__double_as_longlong(sc);
  u = (u >> 63) ? ~u : (u | 0x8000000000000000ULL);  // ascending-sortable
  unsigned long long inv = ~u;                       // descending
  if (!valid) inv = INVALID_KEY;
  keys[t] = (inv & ~0x3FFFULL) | (unsigned long long)i;  // 50-bit score + idx
}

// ---- sort phase A: per-8192-half in-LDS bitonic sort (half0 asc, half1 desc)
__global__ __launch_bounds__(1024) void sortA_k(unsigned long long* __restrict__ keys) {
  __shared__ unsigned long long s[8192];   // 64 KB
  const int half = blockIdx.x & 1;
  unsigned long long* g = keys + (((size_t)(blockIdx.x >> 1)) << 14) + ((size_t)half << 13);
  const int tid = threadIdx.x;
  for (int i = tid; i < 8192; i += 1024) s[i] = g[i];
  for (int size = 2; size <= 8192; size <<= 1) {
    for (int stride = size >> 1; stride > 0; stride >>= 1) {
      __syncthreads();
      for (int u = tid; u < 4096; u += 1024) {
        int lo = u & (stride - 1);
        int i1 = ((u - lo) << 1) | lo;
        int i2 = i1 + stride;
        bool up = (i1 & size) == 0;
        if (half) up = !up;   // upper half sorts descending
        unsigned long long a = s[i1], b = s[i2];
        if ((a > b) == up) { s[i1] = b; s[i2] = a; }
      }
    }
  }
  __syncthreads();
  for (int i = tid; i < 8192; i += 1024) g[i] = s[i];
}

// ---- sort phase B: single global stride-8192 compare-exchange (ascending) --
__global__ __launch_bounds__(256) void sortB_k(unsigned long long* __restrict__ keys) {
  int t = blockIdx.x * 256 + threadIdx.x;   // 4*8192
  int n = t >> 13, i = t & 8191;
  unsigned long long* g = keys + ((size_t)n << 14);
  unsigned long long a = g[i], b = g[i + 8192];
  if (a > b) { g[i] = b; g[i + 8192] = a; }
}

// ---- sort phase C: per-8192-half in-LDS bitonic merge (ascending) ----------
__global__ __launch_bounds__(1024) void sortC_k(unsigned long long* __restrict__ keys) {
  __shared__ unsigned long long s[8192];
  unsigned long long* g = keys + (((size_t)(blockIdx.x >> 1)) << 14) + ((size_t)(blockIdx.x & 1) << 13);
  const int tid = threadIdx.x;
  for (int i = tid; i < 8192; i += 1024) s[i] = g[i];
  for (int stride = 4096; stride > 0; stride >>= 1) {
    __syncthreads();
    for (int u = tid; u < 4096; u += 1024) {
      int lo = u & (stride - 1);
      int i1 = ((u - lo) << 1) | lo;
      int i2 = i1 + stride;
      unsigned long long a = s[i1], b = s[i2];
      if (a > b) { s[i1] = b; s[i2] = a; }
    }
  }
  __syncthreads();
  for (int i = tid; i < 8192; i += 1024) g[i] = s[i];
}

// ---------------- gather sorted top-3000 boxes + valid bit-words ------------
__global__ void gather_k(const unsigned long long* __restrict__ keys,
                         const double* __restrict__ boxes,
                         double* __restrict__ bsort,
                         unsigned long long* __restrict__ vw) {
  int n = blockIdx.y, w = blockIdx.x, l = threadIdx.x;  // 47 x 4 blocks, 64 thr
  int r = w * 64 + l;
  bool valid = false;
  if (r < NPRE) {
    unsigned long long kk = keys[((size_t)n << 14) + r];
    valid = kk < INVALID_KEY;
    unsigned idx = (unsigned)(kk & 0x3FFFULL);
    const double* bp = boxes + ((size_t)n * NA + idx) * 4;
    double* dp = bsort + ((size_t)n * NPRE + r) * 4;
    dp[0] = bp[0]; dp[1] = bp[1]; dp[2] = bp[2]; dp[3] = bp[3];
  }
  unsigned long long mask = __ballot(valid);
  if (l == 0) vw[n * NW + w] = mask;
}

// ------- suppression matrix (fp64 IoU): bit j set iff j>i && iou>0.7 --------
__global__ __launch_bounds__(256) void iou_k(const double* __restrict__ bsort,
                                             unsigned long long* __restrict__ sup) {
  int t = blockIdx.x * 256 + threadIdx.x;
  if (t >= 4 * NPRE * NW) return;
  int w = t % NW; int rest = t / NW; int i = rest % NPRE; int n = rest / NPRE;
  const double* bb = bsort + (size_t)n * NPRE * 4;
  double bix1 = bb[(size_t)i*4], biy1 = bb[(size_t)i*4+1];
  double bix2 = bb[(size_t)i*4+2], biy2 = bb[(size_t)i*4+3];
  double ai = (bix2 - bix1) * (biy2 - biy1);
  unsigned long long word = 0ULL;
  int j0 = w << 6;
  if (j0 + 63 > i) {
    int lmax = NPRE - j0; if (lmax > 64) lmax = 64;
    for (int l = 0; l < lmax; ++l) {
      int j = j0 + l;
      if (j <= i) continue;
      const double* bj = bb + (size_t)j * 4;
      double aj = (bj[2] - bj[0]) * (bj[3] - bj[1]);
      double xx1 = fmax(bix1, bj[0]), yy1 = fmax(biy1, bj[1]);
      double xx2 = fmin(bix2, bj[2]), yy2 = fmin(biy2, bj[3]);
      double inter = fmax(xx2 - xx1, 0.0) * fmax(yy2 - yy1, 0.0);
      double uni = ai + aj - inter;
      double iou = (uni > 0.0) ? inter / uni : 0.0;
      word |= (unsigned long long)(iou > 0.7) << l;
    }
  }
  sup[((size_t)n * NPRE + i) * NW + w] = word;
}

// ------- NMS: block-64 mask propagation (1 wave/batch) + emit rois ----------
__global__ void nms_k(const unsigned long long* __restrict__ sup,
                      const unsigned long long* __restrict__ vwp,
                      const double* __restrict__ bsort,
                      float* __restrict__ out) {
  int n = blockIdx.x; int l = threadIdx.x;   // 64 threads = 1 wave
  unsigned long long vw = (l < NW) ? vwp[n * NW + l] : 0ULL;
  unsigned long long remv = 0ULL, keepw = 0ULL;
  const unsigned long long* sbase = sup + (size_t)n * NPRE * NW;
  for (int b = 0; b < NW; ++b) {
    int gi = b * 64 + l;
    unsigned long long r = (gi < NPRE) ? sbase[(size_t)gi * NW + b] : 0ULL;
    unsigned long long kept = __shfl(vw & ~remv, b);
    // intra-block sequential resolve (kept/todo are wave-uniform)
    unsigned long long todo = kept;
    while (todo) {
      int i = __builtin_ctzll(todo);
      unsigned long long ri = __shfl(r, i);
      kept &= ~ri;
      todo &= todo - 1;
      todo &= ~ri;
    }
    if (l == b) keepw = kept;
    // propagate suppression of kept candidates to all later column-blocks
    unsigned long long m = kept;
    while (m) {
      int i = __builtin_ctzll(m);
      m &= m - 1;
      if (l < NW) remv |= sbase[(size_t)(b * 64 + i) * NW + l];
    }
  }
  unsigned long long keep = keepw;
  int cnt = __popcll(keep);
  int pre = cnt;
#pragma unroll
  for (int d = 1; d < 64; d <<= 1) {
    int tt = __shfl_up(pre, d);
    if (l >= d) pre += tt;
  }
  int nk = __shfl(pre, 63);
  int excl = pre - cnt;
  __shared__ float sbox[NPOST * 4];
  unsigned long long m2 = keep; int rank = excl;
  while (m2) {
    int b = __builtin_ctzll(m2);
    m2 &= m2 - 1;
    if (rank < NPOST) {
      int j = (l << 6) + b;
      const double* bj = bsort + ((size_t)n * NPRE + j) * 4;
      sbox[rank*4]   = (float)bj[0]; sbox[rank*4+1] = (float)bj[1];
      sbox[rank*4+2] = (float)bj[2]; sbox[rank*4+3] = (float)bj[3];
    }
    ++rank;
  }
  __syncthreads();
  if (nk == 0 && l == 0) {
    const double* b0 = bsort + (size_t)n * NPRE * 4;
    sbox[0] = (float)b0[0]; sbox[1] = (float)b0[1];
    sbox[2] = (float)b0[2]; sbox[3] = (float)b0[3];
  }
  __syncthreads();
  int nke = nk > 0 ? nk : 1;
  for (int r = l; r < NPOST; r += 64) {
    int src = r < nke ? r : r % nke;
    float4 b4 = *(float4*)(sbox + src * 4);
    *(float4*)(out + OFF_ROIS + ((size_t)n * NPOST + r) * 4) = b4;
    out[OFF_IDX + n * NPOST + r] = (float)n;
  }
}

extern "C" void kernel_launch(void* const* d_in, const int* in_sizes, int n_in,
                              void* d_out, int out_size, void* d_ws, size_t ws_size,
                              hipStream_t stream) {
  const float* X  = (const float*)d_in[0];
  const float* CW = (const float*)d_in[1];
  const float* CB = (const float*)d_in[2];
  const float* SW = (const float*)d_in[3];
  const float* SB = (const float*)d_in[4];
  const float* LW = (const float*)d_in[5];
  const float* LB = (const float*)d_in[6];
  const int*   IH = (const int*)d_in[7];
  const int*   IW = (const int*)d_in[8];
  float* out = (float*)d_out;
  char* ws = (char*)d_ws;

  // ws carve. sup OVERLAYS feat (feat dead after heads_k). Peak: 14,949,504 B.
  float* feat = (float*)(ws + 0);                                  // 11,829,248
  unsigned long long* sup  = (unsigned long long*)(ws + 0);        //  4,512,000 (overlay)
  float* Wt    = (float*)(ws + 11829248);                          //    131,072
  double* fg   = (double*)(ws + 11960320);                         //    415,872
  double* boxes= (double*)(ws + 12376192);                         //  1,663,488
  unsigned long long* keys = (unsigned long long*)(ws + 14039680); //    524,288
  double* bsort= (double*)(ws + 14563968);                         //    384,000
  unsigned long long* vw   = (unsigned long long*)(ws + 14947968); //      1,536

  hipLaunchKernelGGL(wt_k,     dim3(128),        dim3(256),  0, stream, LW, SW, Wt);
  hipLaunchKernelGGL(conv_k,   dim3(38, 8, 4),   dim3(256),  0, stream, X, CW, CB, feat);
  hipLaunchKernelGGL(heads_k,  dim3(361, 4),     dim3(256),  0, stream, feat, Wt, LB, SB, out, fg);
  hipLaunchKernelGGL(decode_k, dim3(256),        dim3(256),  0, stream, out, out, fg, IH, IW, boxes, keys);
  hipLaunchKernelGGL(sortA_k,  dim3(8),          dim3(1024), 0, stream, keys);
  hipLaunchKernelGGL(sortB_k,  dim3(128),        dim3(256),  0, stream, keys);
  hipLaunchKernelGGL(sortC_k,  dim3(8),          dim3(1024), 0, stream, keys);
  hipLaunchKernelGGL(gather_k, dim3(47, 4),      dim3(64),   0, stream, keys, boxes, bsort, vw);
  hipLaunchKernelGGL(iou_k,    dim3((4*NPRE*NW + 255) / 256), dim3(256), 0, stream, bsort, sup);
  hipLaunchKernelGGL(nms_k,    dim3(4),          dim3(64),   0, stream, sup, vw, bsort, out);
}